// Round 1
// baseline (3049.325 us; speedup 1.0000x reference)
//
#include <hip/hip_runtime.h>
#include <cstdint>
#include <cstddef>

#define L_SEQ 2048
#define DMODEL 1024
#define NHEAD 16
#define DHEAD 64
#define FFN_F 4096
#define VOCAB 32000
#define NLAYER 4

typedef __attribute__((ext_vector_type(8))) short short8;
typedef __attribute__((ext_vector_type(4))) float f32x4;
typedef __attribute__((ext_vector_type(4))) unsigned int u32x4;

__device__ __forceinline__ unsigned short f2bf(float f) {
  unsigned int u = __float_as_uint(f);
  u += 0x7fffu + ((u >> 16) & 1u);
  return (unsigned short)(u >> 16);
}
__device__ __forceinline__ float b2f(unsigned short h) {
  return __uint_as_float(((unsigned int)h) << 16);
}
__device__ __forceinline__ float toF(float v) { return v; }
__device__ __forceinline__ float toF(unsigned short v) { return b2f(v); }

enum { E_F32 = 0, E_BF16 = 1, E_GATE = 2, E_ADD = 3 };

// C[M,N] = alpha * A[M,K] * B[N,K]^T   (both bf16, NT, f32 accum)
template <int EPI>
__global__ __launch_bounds__(256) void gemm_nt(
    const unsigned short* __restrict__ Ag, const unsigned short* __restrict__ Bg,
    void* __restrict__ Cg, int M, int N, int K, int lda, int ldb, int ldc,
    long long sA, long long sB, long long sC, float alpha,
    const float* __restrict__ G, const float* __restrict__ X1,
    const float* __restrict__ X2)
{
  const int bz = blockIdx.z;
  const unsigned short* A = Ag + (size_t)bz * sA;
  const unsigned short* B = Bg + (size_t)bz * sB;
  const int mb = blockIdx.y * 128;
  const int nb = blockIdx.x * 128;

  __shared__ __align__(16) unsigned short As[128 * 40];
  __shared__ __align__(16) unsigned short Bs[128 * 40];

  const int tid = threadIdx.x;
  const int lane = tid & 63;
  const int wave = tid >> 6;
  const int wm = (wave >> 1) * 64;
  const int wn = (wave & 1) * 64;
  const int lr = lane & 15;
  const int lk = (lane >> 4) * 8;

  f32x4 acc[4][4];
#pragma unroll
  for (int i = 0; i < 4; i++)
#pragma unroll
    for (int j = 0; j < 4; j++) acc[i][j] = (f32x4){0.f, 0.f, 0.f, 0.f};

  const int sr = tid >> 2;
  const int sk = (tid & 3) * 8;

  for (int kb = 0; kb < K; kb += 32) {
#pragma unroll
    for (int p = 0; p < 2; p++) {
      int row = sr + p * 64;
      u32x4 va = {0u, 0u, 0u, 0u};
      int gr = mb + row;
      if (gr < M) va = *(const u32x4*)(A + (size_t)gr * lda + kb + sk);
      *(u32x4*)(&As[row * 40 + sk]) = va;
      u32x4 vb = {0u, 0u, 0u, 0u};
      int gn = nb + row;
      if (gn < N) vb = *(const u32x4*)(B + (size_t)gn * ldb + kb + sk);
      *(u32x4*)(&Bs[row * 40 + sk]) = vb;
    }
    __syncthreads();
    short8 af[4], bfr[4];
#pragma unroll
    for (int i = 0; i < 4; i++)
      af[i] = *(const short8*)(&As[(wm + 16 * i + lr) * 40 + lk]);
#pragma unroll
    for (int j = 0; j < 4; j++)
      bfr[j] = *(const short8*)(&Bs[(wn + 16 * j + lr) * 40 + lk]);
#pragma unroll
    for (int i = 0; i < 4; i++)
#pragma unroll
      for (int j = 0; j < 4; j++)
        acc[i][j] = __builtin_amdgcn_mfma_f32_16x16x32_bf16(af[i], bfr[j], acc[i][j], 0, 0, 0);
    __syncthreads();
  }

  const size_t cb = (size_t)bz * sC;
#pragma unroll
  for (int i = 0; i < 4; i++) {
#pragma unroll
    for (int j = 0; j < 4; j++) {
      int oc = nb + wn + 16 * j + lr;
      if (oc >= N) continue;
#pragma unroll
      for (int r = 0; r < 4; r++) {
        int orow = mb + wm + 16 * i + (lane >> 4) * 4 + r;
        if (orow >= M) continue;
        float v = acc[i][j][r] * alpha;
        size_t idx = cb + (size_t)orow * ldc + oc;
        if (EPI == E_F32) {
          ((float*)Cg)[idx] = v;
        } else if (EPI == E_BF16) {
          ((unsigned short*)Cg)[idx] = f2bf(v);
        } else if (EPI == E_GATE) {
          float g = G[idx];
          float sw = g / (1.0f + expf(-g));
          ((unsigned short*)Cg)[idx] = f2bf(sw * v);
        } else {
          ((float*)Cg)[idx] = X1[idx] + X2[idx] + v;
        }
      }
    }
  }
}

__global__ __launch_bounds__(256) void rmsnorm_kernel(
    const float* __restrict__ x, const float* __restrict__ scale,
    unsigned short* __restrict__ out)
{
  int row = blockIdx.x;
  const float* xr = x + (size_t)row * DMODEL;
  int tid = threadIdx.x;
  float v[4];
  float ss = 0.f;
#pragma unroll
  for (int i = 0; i < 4; i++) {
    v[i] = xr[tid + 256 * i];
    ss += v[i] * v[i];
  }
#pragma unroll
  for (int o = 32; o > 0; o >>= 1) ss += __shfl_xor(ss, o);
  __shared__ float red[4];
  if ((tid & 63) == 0) red[tid >> 6] = ss;
  __syncthreads();
  ss = red[0] + red[1] + red[2] + red[3];
  float inv = rsqrtf(ss / DMODEL + 1e-6f);
#pragma unroll
  for (int i = 0; i < 4; i++) {
    int d = tid + 256 * i;
    out[(size_t)row * DMODEL + d] = f2bf(v[i] * inv * scale[d]);
  }
}

__global__ __launch_bounds__(256) void softmax_kernel(unsigned short* __restrict__ S)
{
  int i = blockIdx.x;
  int h = blockIdx.y;
  unsigned short* row = S + ((size_t)h * L_SEQ + i) * L_SEQ;
  int n = i + 1;
  int tid = threadIdx.x;
  float mx = -3.4e38f;
  for (int j = tid; j < n; j += 256) mx = fmaxf(mx, b2f(row[j]));
#pragma unroll
  for (int o = 32; o > 0; o >>= 1) mx = fmaxf(mx, __shfl_xor(mx, o));
  __shared__ float red[4];
  if ((tid & 63) == 0) red[tid >> 6] = mx;
  __syncthreads();
  mx = fmaxf(fmaxf(red[0], red[1]), fmaxf(red[2], red[3]));
  float sum = 0.f;
  for (int j = tid; j < n; j += 256) sum += expf(b2f(row[j]) - mx);
#pragma unroll
  for (int o = 32; o > 0; o >>= 1) sum += __shfl_xor(sum, o);
  __syncthreads();
  if ((tid & 63) == 0) red[tid >> 6] = sum;
  __syncthreads();
  sum = red[0] + red[1] + red[2] + red[3];
  float inv = 1.0f / sum;
  for (int j = tid; j < L_SEQ; j += 256) {
    float p = (j < n) ? expf(b2f(row[j]) - mx) * inv : 0.0f;
    row[j] = f2bf(p);
  }
}

template <typename Tin>
__global__ __launch_bounds__(256) void transpose_to_bf16(
    const Tin* __restrict__ in, unsigned short* __restrict__ out, int R, int C)
{
  __shared__ float tile[32][33];
  int c0 = blockIdx.x * 32;
  int r0 = blockIdx.y * 32;
  int tx = threadIdx.x;
  int ty = threadIdx.y;
#pragma unroll
  for (int j = 0; j < 32; j += 8)
    tile[ty + j][tx] = toF(in[(size_t)(r0 + ty + j) * C + c0 + tx]);
  __syncthreads();
#pragma unroll
  for (int j = 0; j < 32; j += 8)
    out[(size_t)(c0 + ty + j) * R + r0 + tx] = f2bf(tile[tx][ty + j]);
}

__global__ __launch_bounds__(256) void convert_f2b_kernel(
    const float* __restrict__ in, unsigned short* __restrict__ out, size_t n)
{
  size_t i = ((size_t)blockIdx.x * 256 + threadIdx.x) * 4;
  if (i + 3 < n) {
    float4 v = *(const float4*)(in + i);
    out[i] = f2bf(v.x);
    out[i + 1] = f2bf(v.y);
    out[i + 2] = f2bf(v.z);
    out[i + 3] = f2bf(v.w);
  }
}

__global__ __launch_bounds__(256) void embed_kernel(
    const int* __restrict__ ids, const float* __restrict__ emb,
    const float* __restrict__ pos, float* __restrict__ x)
{
  int l = blockIdx.x;
  int id = ids[l];
#pragma unroll
  for (int i = 0; i < 4; i++) {
    int d = threadIdx.x + 256 * i;
    x[(size_t)l * DMODEL + d] = emb[(size_t)id * DMODEL + d] + pos[(size_t)l * DMODEL + d];
  }
}

extern "C" void kernel_launch(void* const* d_in, const int* in_sizes, int n_in,
                              void* d_out, int out_size, void* d_ws, size_t ws_size,
                              hipStream_t stream)
{
  const int L = L_SEQ, D = DMODEL, F = FFN_F, V = VOCAB;
  const int* ids = (const int*)d_in[0];
  const float* embed = (const float*)d_in[1];
  const float* pos = (const float*)d_in[2];
  const float* wq = (const float*)d_in[3];
  const float* wk = (const float*)d_in[4];
  const float* wv = (const float*)d_in[5];
  const float* wo = (const float*)d_in[6];
  const float* gatew = (const float*)d_in[7];
  const float* valw = (const float*)d_in[8];
  const float* ffow = (const float*)d_in[9];
  const float* ln1 = (const float*)d_in[10];
  const float* ln2 = (const float*)d_in[11];
  const float* lnf = (const float*)d_in[12];

  char* ws = (char*)d_ws;
  size_t off = 0;
  auto alloc = [&](size_t bytes) -> void* {
    void* p = ws + off;
    off += (bytes + 255) & ~(size_t)255;
    return p;
  };
  float* x = (float*)alloc((size_t)L * D * 4);
  unsigned short* xn = (unsigned short*)alloc((size_t)L * D * 2);
  unsigned short* qb = (unsigned short*)alloc((size_t)L * D * 2);
  unsigned short* kb = (unsigned short*)alloc((size_t)L * D * 2);
  unsigned short* vb = (unsigned short*)alloc((size_t)L * D * 2);
  unsigned short* vtb = (unsigned short*)alloc((size_t)L * D * 2);
  unsigned short* atb = (unsigned short*)alloc((size_t)L * D * 2);
  float* afp = (float*)alloc((size_t)L * D * 4);
  unsigned short* hb = (unsigned short*)alloc((size_t)L * F * 2);
  unsigned short* wqt = (unsigned short*)alloc((size_t)D * D * 2);
  unsigned short* wkt = (unsigned short*)alloc((size_t)D * D * 2);
  unsigned short* wvt = (unsigned short*)alloc((size_t)D * D * 2);
  unsigned short* wot = (unsigned short*)alloc((size_t)D * D * 2);
  unsigned short* gt = (unsigned short*)alloc((size_t)D * F * 2);
  unsigned short* vtw = (unsigned short*)alloc((size_t)D * F * 2);
  unsigned short* fot = (unsigned short*)alloc((size_t)F * D * 2);
  unsigned short* embb = (unsigned short*)alloc((size_t)V * D * 2);

  // d_out scratch: S (bf16, 16*L*L) at offset 0; g (f32, L*F) after it
  unsigned short* S = (unsigned short*)d_out;
  float* gbuf = (float*)((char*)d_out + (size_t)151000064);

  dim3 blk(256);
  dim3 blkT(32, 8);

  auto gemm = [&](int epi, const unsigned short* A, const unsigned short* B, void* C,
                  int M, int N, int K, int lda, int ldb, int ldc,
                  long long sA, long long sB, long long sC, int batch, float alpha,
                  const float* G, const float* X1, const float* X2) {
    dim3 grid((N + 127) / 128, (M + 127) / 128, batch);
    if (epi == E_F32)
      gemm_nt<E_F32><<<grid, blk, 0, stream>>>(A, B, C, M, N, K, lda, ldb, ldc, sA, sB, sC, alpha, G, X1, X2);
    else if (epi == E_BF16)
      gemm_nt<E_BF16><<<grid, blk, 0, stream>>>(A, B, C, M, N, K, lda, ldb, ldc, sA, sB, sC, alpha, G, X1, X2);
    else if (epi == E_GATE)
      gemm_nt<E_GATE><<<grid, blk, 0, stream>>>(A, B, C, M, N, K, lda, ldb, ldc, sA, sB, sC, alpha, G, X1, X2);
    else
      gemm_nt<E_ADD><<<grid, blk, 0, stream>>>(A, B, C, M, N, K, lda, ldb, ldc, sA, sB, sC, alpha, G, X1, X2);
  };

  embed_kernel<<<L, blk, 0, stream>>>(ids, embed, pos, x);
  convert_f2b_kernel<<<(unsigned)((size_t)V * D / 1024), blk, 0, stream>>>(embed, embb, (size_t)V * D);

  for (int i = 0; i < NLAYER; i++) {
    const float* wqi = wq + (size_t)i * D * D;
    const float* wki = wk + (size_t)i * D * D;
    const float* wvi = wv + (size_t)i * D * D;
    const float* woi = wo + (size_t)i * D * D;
    const float* gi = gatew + (size_t)i * D * F;
    const float* vi = valw + (size_t)i * D * F;
    const float* fi = ffow + (size_t)i * F * D;

    transpose_to_bf16<float><<<dim3(D / 32, D / 32), blkT, 0, stream>>>(wqi, wqt, D, D);
    transpose_to_bf16<float><<<dim3(D / 32, D / 32), blkT, 0, stream>>>(wki, wkt, D, D);
    transpose_to_bf16<float><<<dim3(D / 32, D / 32), blkT, 0, stream>>>(wvi, wvt, D, D);
    transpose_to_bf16<float><<<dim3(D / 32, D / 32), blkT, 0, stream>>>(woi, wot, D, D);
    transpose_to_bf16<float><<<dim3(F / 32, D / 32), blkT, 0, stream>>>(gi, gt, D, F);
    transpose_to_bf16<float><<<dim3(F / 32, D / 32), blkT, 0, stream>>>(vi, vtw, D, F);
    transpose_to_bf16<float><<<dim3(D / 32, F / 32), blkT, 0, stream>>>(fi, fot, F, D);

    rmsnorm_kernel<<<L, blk, 0, stream>>>(x, ln1 + (size_t)i * D, xn);

    gemm(E_BF16, xn, wqt, qb, L, D, D, D, D, D, 0, 0, 0, 1, 1.0f, nullptr, nullptr, nullptr);
    gemm(E_BF16, xn, wkt, kb, L, D, D, D, D, D, 0, 0, 0, 1, 1.0f, nullptr, nullptr, nullptr);
    gemm(E_BF16, xn, wvt, vb, L, D, D, D, D, D, 0, 0, 0, 1, 1.0f, nullptr, nullptr, nullptr);

    transpose_to_bf16<unsigned short><<<dim3(D / 32, L / 32), blkT, 0, stream>>>(vb, vtb, L, D);

    // S[h] = alpha * Q_h K_h^T : batched over heads
    gemm(E_BF16, qb, kb, S, L, L, DHEAD, D, D, L,
         64, 64, (long long)L * L, NHEAD, 0.125f, nullptr, nullptr, nullptr);

    softmax_kernel<<<dim3(L, NHEAD), blk, 0, stream>>>(S);

    // O_h = P_h V_h
    gemm(E_BF16, S, vtb, atb, L, DHEAD, L, L, L, D,
         (long long)L * L, (long long)DHEAD * L, 64, NHEAD, 1.0f, nullptr, nullptr, nullptr);

    gemm(E_F32, atb, wot, afp, L, D, D, D, D, D, 0, 0, 0, 1, 1.0f, nullptr, nullptr, nullptr);

    rmsnorm_kernel<<<L, blk, 0, stream>>>(x, ln2 + (size_t)i * D, xn);

    gemm(E_F32, xn, gt, gbuf, L, F, D, D, D, F, 0, 0, 0, 1, 1.0f, nullptr, nullptr, nullptr);
    gemm(E_GATE, xn, vtw, hb, L, F, D, D, D, F, 0, 0, 0, 1, 1.0f, gbuf, nullptr, nullptr);
    gemm(E_ADD, hb, fot, x, L, D, F, F, F, D, 0, 0, 0, 1, 1.0f, nullptr, x, afp);
  }

  rmsnorm_kernel<<<L, blk, 0, stream>>>(x, lnf, xn);
  gemm(E_F32, xn, embb, d_out, L, V, D, D, D, V, 0, 0, 0, 1, 1.0f, nullptr, nullptr, nullptr);
}

// Round 2
// 1993.774 us; speedup vs baseline: 1.5294x; 1.5294x over previous
//
#include <hip/hip_runtime.h>
#include <cstdint>
#include <cstddef>

#define L_SEQ 2048
#define DMODEL 1024
#define NHEAD 16
#define DHEAD 64
#define FFN_F 4096
#define VOCAB 32000
#define NLAYER 4

typedef __attribute__((ext_vector_type(8))) short short8;
typedef __attribute__((ext_vector_type(4))) float f32x4;
typedef __attribute__((ext_vector_type(4))) unsigned int u32x4;

__device__ __forceinline__ unsigned short f2bf(float f) {
  unsigned int u = __float_as_uint(f);
  u += 0x7fffu + ((u >> 16) & 1u);
  return (unsigned short)(u >> 16);
}
__device__ __forceinline__ float b2f(unsigned short h) {
  return __uint_as_float(((unsigned int)h) << 16);
}
__device__ __forceinline__ float toF(float v) { return v; }
__device__ __forceinline__ float toF(unsigned short v) { return b2f(v); }

__device__ __forceinline__ void glds16(const unsigned short* g, unsigned short* l) {
  __builtin_amdgcn_global_load_lds(
      (const __attribute__((address_space(1))) unsigned int*)g,
      (__attribute__((address_space(3))) unsigned int*)l, 16, 0, 0);
}

enum { E_F32 = 0, E_BF16 = 1, E_GATE = 2, E_ADD = 3 };

// ---------------- fast path: all dims multiples (M,N %128, K %64) ------------
// C[M,N] = alpha * A[M,K] * B[N,K]^T, bf16 in, f32 accum.
// m97 structure: global_load_lds(16B) -> linear LDS [128][64] with XOR
// slot-swizzle applied on SOURCE addr (write) and ds_read addr (read).
template <int EPI>
__global__ __launch_bounds__(256) void gemm_fast(
    const unsigned short* __restrict__ Ag, const unsigned short* __restrict__ Bg,
    void* __restrict__ Cg, int M, int N, int K, int lda, int ldb, int ldc,
    long long sA, long long sB, long long sC, float alpha, int causal,
    const float* __restrict__ G, const float* __restrict__ X1,
    const float* __restrict__ X2)
{
  const int mb = blockIdx.y * 128;
  const int nb = blockIdx.x * 128;
  if (causal && nb > mb + 127) return;  // fully-masked S block
  const int bz = blockIdx.z;
  const unsigned short* A = Ag + (size_t)bz * sA;
  const unsigned short* B = Bg + (size_t)bz * sB;

  __shared__ __align__(16) unsigned short As[128 * 64];
  __shared__ __align__(16) unsigned short Bs[128 * 64];

  const int tid = threadIdx.x;
  const int lane = tid & 63;
  const int wave = tid >> 6;
  const int wm = (wave >> 1) * 64;
  const int wn = (wave & 1) * 64;
  const int lr = lane & 15;
  const int lg = lane >> 4;

  // staging geometry: each glds writes 8 rows x 64 cols (1KB), lane l ->
  // row l/8, 16B slot l%8. Source col pre-swizzled: slot ^ (row&7).
  const int srow = lane >> 3;
  const int scol = ((lane & 7) ^ srow) * 8;

  f32x4 acc[4][4];
#pragma unroll
  for (int i = 0; i < 4; i++)
#pragma unroll
    for (int j = 0; j < 4; j++) acc[i][j] = (f32x4){0.f, 0.f, 0.f, 0.f};

  const unsigned short* Abase = A + (size_t)(mb + wave * 32 + srow) * lda + scol;
  const unsigned short* Bbase = B + (size_t)(nb + wave * 32 + srow) * ldb + scol;

  for (int kb = 0; kb < K; kb += 64) {
#pragma unroll
    for (int c = 0; c < 4; c++)
      glds16(Abase + (size_t)(c * 8) * lda + kb, &As[(wave * 32 + c * 8) * 64]);
#pragma unroll
    for (int c = 0; c < 4; c++)
      glds16(Bbase + (size_t)(c * 8) * ldb + kb, &Bs[(wave * 32 + c * 8) * 64]);
    __syncthreads();

    short8 af[2][4], bfb[2][4];
#pragma unroll
    for (int h = 0; h < 2; h++) {
      const int swz = ((h * 4 + lg) ^ (lr & 7)) * 8;
#pragma unroll
      for (int i = 0; i < 4; i++) {
        af[h][i] = *(const short8*)&As[(wm + 16 * i + lr) * 64 + swz];
        bfb[h][i] = *(const short8*)&Bs[(wn + 16 * i + lr) * 64 + swz];
      }
    }
#pragma unroll
    for (int h = 0; h < 2; h++)
#pragma unroll
      for (int i = 0; i < 4; i++)
#pragma unroll
        for (int j = 0; j < 4; j++)
          acc[i][j] = __builtin_amdgcn_mfma_f32_16x16x32_bf16(af[h][i], bfb[h][j], acc[i][j], 0, 0, 0);
    __syncthreads();
  }

  const size_t cb = (size_t)bz * sC;
#pragma unroll
  for (int i = 0; i < 4; i++) {
#pragma unroll
    for (int j = 0; j < 4; j++) {
      int oc = nb + wn + 16 * j + lr;
#pragma unroll
      for (int r = 0; r < 4; r++) {
        int orow = mb + wm + 16 * i + lg * 4 + r;
        float v = acc[i][j][r] * alpha;
        size_t idx = cb + (size_t)orow * ldc + oc;
        if (EPI == E_F32) {
          ((float*)Cg)[idx] = v;
        } else if (EPI == E_BF16) {
          ((unsigned short*)Cg)[idx] = f2bf(v);
        } else if (EPI == E_GATE) {
          float g = G[idx];
          float sw = g / (1.0f + expf(-g));
          ((unsigned short*)Cg)[idx] = f2bf(sw * v);
        } else {
          ((float*)Cg)[idx] = X1[idx] + X2[idx] + v;
        }
      }
    }
  }
}

// ---------------- general path (PV only: N=64) -------------------------------
template <int EPI>
__global__ __launch_bounds__(256) void gemm_nt(
    const unsigned short* __restrict__ Ag, const unsigned short* __restrict__ Bg,
    void* __restrict__ Cg, int M, int N, int K, int lda, int ldb, int ldc,
    long long sA, long long sB, long long sC, float alpha, int causal)
{
  const int bz = blockIdx.z;
  const unsigned short* A = Ag + (size_t)bz * sA;
  const unsigned short* B = Bg + (size_t)bz * sB;
  const int mb = blockIdx.y * 128;
  const int nb = blockIdx.x * 128;
  const int Klim = causal ? min(K, mb + 128) : K;

  __shared__ __align__(16) unsigned short As[128 * 40];
  __shared__ __align__(16) unsigned short Bs[128 * 40];

  const int tid = threadIdx.x;
  const int lane = tid & 63;
  const int wave = tid >> 6;
  const int wm = (wave >> 1) * 64;
  const int wn = (wave & 1) * 64;
  const int lr = lane & 15;
  const int lk = (lane >> 4) * 8;

  f32x4 acc[4][4];
#pragma unroll
  for (int i = 0; i < 4; i++)
#pragma unroll
    for (int j = 0; j < 4; j++) acc[i][j] = (f32x4){0.f, 0.f, 0.f, 0.f};

  const int sr = tid >> 2;
  const int sk = (tid & 3) * 8;

  for (int kb = 0; kb < Klim; kb += 32) {
#pragma unroll
    for (int p = 0; p < 2; p++) {
      int row = sr + p * 64;
      u32x4 va = {0u, 0u, 0u, 0u};
      int gr = mb + row;
      if (gr < M) va = *(const u32x4*)(A + (size_t)gr * lda + kb + sk);
      *(u32x4*)(&As[row * 40 + sk]) = va;
      u32x4 vb = {0u, 0u, 0u, 0u};
      int gn = nb + row;
      if (gn < N) vb = *(const u32x4*)(B + (size_t)gn * ldb + kb + sk);
      *(u32x4*)(&Bs[row * 40 + sk]) = vb;
    }
    __syncthreads();
    short8 af[4], bfr[4];
#pragma unroll
    for (int i = 0; i < 4; i++)
      af[i] = *(const short8*)(&As[(wm + 16 * i + lr) * 40 + lk]);
#pragma unroll
    for (int j = 0; j < 4; j++)
      bfr[j] = *(const short8*)(&Bs[(wn + 16 * j + lr) * 40 + lk]);
#pragma unroll
    for (int i = 0; i < 4; i++)
#pragma unroll
      for (int j = 0; j < 4; j++)
        acc[i][j] = __builtin_amdgcn_mfma_f32_16x16x32_bf16(af[i], bfr[j], acc[i][j], 0, 0, 0);
    __syncthreads();
  }

  const size_t cb = (size_t)bz * sC;
#pragma unroll
  for (int i = 0; i < 4; i++) {
#pragma unroll
    for (int j = 0; j < 4; j++) {
      int oc = nb + wn + 16 * j + lr;
      if (oc >= N) continue;
#pragma unroll
      for (int r = 0; r < 4; r++) {
        int orow = mb + wm + 16 * i + (lane >> 4) * 4 + r;
        if (orow >= M) continue;
        float v = acc[i][j][r] * alpha;
        size_t idx = cb + (size_t)orow * ldc + oc;
        if (EPI == E_BF16) ((unsigned short*)Cg)[idx] = f2bf(v);
        else ((float*)Cg)[idx] = v;
      }
    }
  }
}

__global__ __launch_bounds__(256) void rmsnorm_kernel(
    const float* __restrict__ x, const float* __restrict__ scale,
    unsigned short* __restrict__ out)
{
  int row = blockIdx.x;
  const float* xr = x + (size_t)row * DMODEL;
  int tid = threadIdx.x;
  float v[4];
  float ss = 0.f;
#pragma unroll
  for (int i = 0; i < 4; i++) {
    v[i] = xr[tid + 256 * i];
    ss += v[i] * v[i];
  }
#pragma unroll
  for (int o = 32; o > 0; o >>= 1) ss += __shfl_xor(ss, o);
  __shared__ float red[4];
  if ((tid & 63) == 0) red[tid >> 6] = ss;
  __syncthreads();
  ss = red[0] + red[1] + red[2] + red[3];
  float inv = rsqrtf(ss / DMODEL + 1e-6f);
#pragma unroll
  for (int i = 0; i < 4; i++) {
    int d = tid + 256 * i;
    out[(size_t)row * DMODEL + d] = f2bf(v[i] * inv * scale[d]);
  }
}

__global__ __launch_bounds__(256) void softmax_kernel(unsigned short* __restrict__ S)
{
  int i = blockIdx.x;
  int h = blockIdx.y;
  unsigned short* row = S + ((size_t)h * L_SEQ + i) * L_SEQ;
  int n = i + 1;
  int wlim = ((i >> 7) + 1) << 7;  // PV only reads cols < this (causal K-limit)
  int tid = threadIdx.x;
  float mx = -3.4e38f;
  for (int j = tid; j < n; j += 256) mx = fmaxf(mx, b2f(row[j]));
#pragma unroll
  for (int o = 32; o > 0; o >>= 1) mx = fmaxf(mx, __shfl_xor(mx, o));
  __shared__ float red[4];
  if ((tid & 63) == 0) red[tid >> 6] = mx;
  __syncthreads();
  mx = fmaxf(fmaxf(red[0], red[1]), fmaxf(red[2], red[3]));
  float sum = 0.f;
  for (int j = tid; j < n; j += 256) sum += expf(b2f(row[j]) - mx);
#pragma unroll
  for (int o = 32; o > 0; o >>= 1) sum += __shfl_xor(sum, o);
  __syncthreads();
  if ((tid & 63) == 0) red[tid >> 6] = sum;
  __syncthreads();
  sum = red[0] + red[1] + red[2] + red[3];
  float inv = 1.0f / sum;
  for (int j = tid; j < wlim; j += 256) {
    float p = (j < n) ? expf(b2f(row[j]) - mx) * inv : 0.0f;
    row[j] = f2bf(p);
  }
}

template <typename Tin>
__global__ __launch_bounds__(256) void transpose_to_bf16(
    const Tin* __restrict__ in, unsigned short* __restrict__ out, int R, int C)
{
  __shared__ float tile[32][33];
  int c0 = blockIdx.x * 32;
  int r0 = blockIdx.y * 32;
  int tx = threadIdx.x;
  int ty = threadIdx.y;
#pragma unroll
  for (int j = 0; j < 32; j += 8)
    tile[ty + j][tx] = toF(in[(size_t)(r0 + ty + j) * C + c0 + tx]);
  __syncthreads();
#pragma unroll
  for (int j = 0; j < 32; j += 8)
    out[(size_t)(c0 + ty + j) * R + r0 + tx] = f2bf(tile[tx][ty + j]);
}

__global__ __launch_bounds__(256) void convert_f2b_kernel(
    const float* __restrict__ in, unsigned short* __restrict__ out, size_t n)
{
  size_t i = ((size_t)blockIdx.x * 256 + threadIdx.x) * 4;
  if (i + 3 < n) {
    float4 v = *(const float4*)(in + i);
    out[i] = f2bf(v.x);
    out[i + 1] = f2bf(v.y);
    out[i + 2] = f2bf(v.z);
    out[i + 3] = f2bf(v.w);
  }
}

__global__ __launch_bounds__(256) void embed_kernel(
    const int* __restrict__ ids, const float* __restrict__ emb,
    const float* __restrict__ pos, float* __restrict__ x)
{
  int l = blockIdx.x;
  int id = ids[l];
#pragma unroll
  for (int i = 0; i < 4; i++) {
    int d = threadIdx.x + 256 * i;
    x[(size_t)l * DMODEL + d] = emb[(size_t)id * DMODEL + d] + pos[(size_t)l * DMODEL + d];
  }
}

extern "C" void kernel_launch(void* const* d_in, const int* in_sizes, int n_in,
                              void* d_out, int out_size, void* d_ws, size_t ws_size,
                              hipStream_t stream)
{
  const int L = L_SEQ, D = DMODEL, F = FFN_F, V = VOCAB;
  const int* ids = (const int*)d_in[0];
  const float* embed = (const float*)d_in[1];
  const float* pos = (const float*)d_in[2];
  const float* wq = (const float*)d_in[3];
  const float* wk = (const float*)d_in[4];
  const float* wv = (const float*)d_in[5];
  const float* wo = (const float*)d_in[6];
  const float* gatew = (const float*)d_in[7];
  const float* valw = (const float*)d_in[8];
  const float* ffow = (const float*)d_in[9];
  const float* ln1 = (const float*)d_in[10];
  const float* ln2 = (const float*)d_in[11];
  const float* lnf = (const float*)d_in[12];

  char* ws = (char*)d_ws;
  size_t off = 0;
  auto alloc = [&](size_t bytes) -> void* {
    void* p = ws + off;
    off += (bytes + 255) & ~(size_t)255;
    return p;
  };
  float* x = (float*)alloc((size_t)L * D * 4);
  unsigned short* xn = (unsigned short*)alloc((size_t)L * D * 2);
  unsigned short* qb = (unsigned short*)alloc((size_t)L * D * 2);
  unsigned short* kb = (unsigned short*)alloc((size_t)L * D * 2);
  unsigned short* vb = (unsigned short*)alloc((size_t)L * D * 2);
  unsigned short* vtb = (unsigned short*)alloc((size_t)L * D * 2);
  unsigned short* atb = (unsigned short*)alloc((size_t)L * D * 2);
  float* afp = (float*)alloc((size_t)L * D * 4);
  unsigned short* hb = (unsigned short*)alloc((size_t)L * F * 2);
  unsigned short* wqt = (unsigned short*)alloc((size_t)D * D * 2);
  unsigned short* wkt = (unsigned short*)alloc((size_t)D * D * 2);
  unsigned short* wvt = (unsigned short*)alloc((size_t)D * D * 2);
  unsigned short* wot = (unsigned short*)alloc((size_t)D * D * 2);
  unsigned short* gt = (unsigned short*)alloc((size_t)D * F * 2);
  unsigned short* vtw = (unsigned short*)alloc((size_t)D * F * 2);
  unsigned short* fot = (unsigned short*)alloc((size_t)F * D * 2);
  unsigned short* embb = (unsigned short*)alloc((size_t)V * D * 2);

  unsigned short* S = (unsigned short*)d_out;
  float* gbuf = (float*)((char*)d_out + (size_t)151000064);

  dim3 blk(256);
  dim3 blkT(32, 8);

  auto gemmF = [&](int epi, const unsigned short* A, const unsigned short* B, void* C,
                   int M, int N, int K, int lda, int ldb, int ldc,
                   long long sA, long long sB, long long sC, int batch, float alpha,
                   int causal, const float* G, const float* X1, const float* X2) {
    dim3 grid(N / 128, M / 128, batch);
    if (epi == E_F32)
      gemm_fast<E_F32><<<grid, blk, 0, stream>>>(A, B, C, M, N, K, lda, ldb, ldc, sA, sB, sC, alpha, causal, G, X1, X2);
    else if (epi == E_BF16)
      gemm_fast<E_BF16><<<grid, blk, 0, stream>>>(A, B, C, M, N, K, lda, ldb, ldc, sA, sB, sC, alpha, causal, G, X1, X2);
    else if (epi == E_GATE)
      gemm_fast<E_GATE><<<grid, blk, 0, stream>>>(A, B, C, M, N, K, lda, ldb, ldc, sA, sB, sC, alpha, causal, G, X1, X2);
    else
      gemm_fast<E_ADD><<<grid, blk, 0, stream>>>(A, B, C, M, N, K, lda, ldb, ldc, sA, sB, sC, alpha, causal, G, X1, X2);
  };

  embed_kernel<<<L, blk, 0, stream>>>(ids, embed, pos, x);
  convert_f2b_kernel<<<(unsigned)((size_t)V * D / 1024), blk, 0, stream>>>(embed, embb, (size_t)V * D);

  for (int i = 0; i < NLAYER; i++) {
    const float* wqi = wq + (size_t)i * D * D;
    const float* wki = wk + (size_t)i * D * D;
    const float* wvi = wv + (size_t)i * D * D;
    const float* woi = wo + (size_t)i * D * D;
    const float* gi = gatew + (size_t)i * D * F;
    const float* vi = valw + (size_t)i * D * F;
    const float* fi = ffow + (size_t)i * F * D;

    transpose_to_bf16<float><<<dim3(D / 32, D / 32), blkT, 0, stream>>>(wqi, wqt, D, D);
    transpose_to_bf16<float><<<dim3(D / 32, D / 32), blkT, 0, stream>>>(wki, wkt, D, D);
    transpose_to_bf16<float><<<dim3(D / 32, D / 32), blkT, 0, stream>>>(wvi, wvt, D, D);
    transpose_to_bf16<float><<<dim3(D / 32, D / 32), blkT, 0, stream>>>(woi, wot, D, D);
    transpose_to_bf16<float><<<dim3(F / 32, D / 32), blkT, 0, stream>>>(gi, gt, D, F);
    transpose_to_bf16<float><<<dim3(F / 32, D / 32), blkT, 0, stream>>>(vi, vtw, D, F);
    transpose_to_bf16<float><<<dim3(D / 32, F / 32), blkT, 0, stream>>>(fi, fot, F, D);

    rmsnorm_kernel<<<L, blk, 0, stream>>>(x, ln1 + (size_t)i * D, xn);

    gemmF(E_BF16, xn, wqt, qb, L, D, D, D, D, D, 0, 0, 0, 1, 1.0f, 0, nullptr, nullptr, nullptr);
    gemmF(E_BF16, xn, wkt, kb, L, D, D, D, D, D, 0, 0, 0, 1, 1.0f, 0, nullptr, nullptr, nullptr);
    gemmF(E_BF16, xn, wvt, vb, L, D, D, D, D, D, 0, 0, 0, 1, 1.0f, 0, nullptr, nullptr, nullptr);

    transpose_to_bf16<unsigned short><<<dim3(D / 32, L / 32), blkT, 0, stream>>>(vb, vtb, L, D);

    // S[h] = alpha * Q_h K_h^T (batched over heads, causal block skip)
    gemmF(E_BF16, qb, kb, S, L, L, DHEAD, D, D, L,
          64, 64, (long long)L * L, NHEAD, 0.125f, 1, nullptr, nullptr, nullptr);

    softmax_kernel<<<dim3(L, NHEAD), blk, 0, stream>>>(S);

    // O_h = P_h V_h  (general path, N=64; causal K-limit)
    {
      dim3 grid((DHEAD + 127) / 128, L / 128, NHEAD);
      gemm_nt<E_BF16><<<grid, blk, 0, stream>>>(S, vtb, atb, L, DHEAD, L, L, L, D,
          (long long)L * L, (long long)DHEAD * L, 64, 1.0f, 1);
    }

    gemmF(E_F32, atb, wot, afp, L, D, D, D, D, D, 0, 0, 0, 1, 1.0f, 0, nullptr, nullptr, nullptr);

    rmsnorm_kernel<<<L, blk, 0, stream>>>(x, ln2 + (size_t)i * D, xn);

    gemmF(E_F32, xn, gt, gbuf, L, F, D, D, D, F, 0, 0, 0, 1, 1.0f, 0, nullptr, nullptr, nullptr);
    gemmF(E_GATE, xn, vtw, hb, L, F, D, D, D, F, 0, 0, 0, 1, 1.0f, 0, gbuf, nullptr, nullptr);
    gemmF(E_ADD, hb, fot, x, L, D, F, F, F, D, 0, 0, 0, 1, 1.0f, 0, nullptr, x, afp);
  }

  rmsnorm_kernel<<<L, blk, 0, stream>>>(x, lnf, xn);
  gemmF(E_F32, xn, embb, d_out, L, V, D, D, D, V, 0, 0, 0, 1, 1.0f, 0, nullptr, nullptr, nullptr);
}

// Round 3
// 1499.521 us; speedup vs baseline: 2.0335x; 1.3296x over previous
//
#include <hip/hip_runtime.h>
#include <cstdint>
#include <cstddef>

#define L_SEQ 2048
#define DMODEL 1024
#define NHEAD 16
#define DHEAD 64
#define FFN_F 4096
#define VOCAB 32000
#define NLAYER 4

typedef __attribute__((ext_vector_type(8))) short short8;
typedef __attribute__((ext_vector_type(4))) float f32x4;
typedef __attribute__((ext_vector_type(4))) unsigned int u32x4;

__device__ __forceinline__ unsigned short f2bf(float f) {
  unsigned int u = __float_as_uint(f);
  u += 0x7fffu + ((u >> 16) & 1u);
  return (unsigned short)(u >> 16);
}
__device__ __forceinline__ float b2f(unsigned short h) {
  return __uint_as_float(((unsigned int)h) << 16);
}
__device__ __forceinline__ float toF(float v) { return v; }
__device__ __forceinline__ float toF(unsigned short v) { return b2f(v); }

__device__ __forceinline__ void glds16(const unsigned short* g, unsigned short* l) {
  __builtin_amdgcn_global_load_lds(
      (const __attribute__((address_space(1))) unsigned int*)g,
      (__attribute__((address_space(3))) unsigned int*)l, 16, 0, 0);
}

__device__ __forceinline__ float rmax16(float v) {
  v = fmaxf(v, __shfl_xor(v, 1));
  v = fmaxf(v, __shfl_xor(v, 2));
  v = fmaxf(v, __shfl_xor(v, 4));
  v = fmaxf(v, __shfl_xor(v, 8));
  return v;
}
__device__ __forceinline__ float rsum16(float v) {
  v += __shfl_xor(v, 1);
  v += __shfl_xor(v, 2);
  v += __shfl_xor(v, 4);
  v += __shfl_xor(v, 8);
  return v;
}

enum { E_F32 = 0, E_BF16 = 1, E_GATE = 2, E_ADD = 3 };

// ---------------- dense GEMM: C[M,N] = alpha*A[M,K]*B[N,K]^T -----------------
template <int EPI>
__global__ __launch_bounds__(256) void gemm_fast(
    const unsigned short* __restrict__ Ag, const unsigned short* __restrict__ Bg,
    void* __restrict__ Cg, int M, int N, int K, int lda, int ldb, int ldc,
    long long sA, long long sB, long long sC, float alpha, int causal,
    const float* __restrict__ G, const float* __restrict__ X1,
    const float* __restrict__ X2)
{
  const int mb = blockIdx.y * 128;
  const int nb = blockIdx.x * 128;
  if (causal && nb > mb + 127) return;
  const int bz = blockIdx.z;
  const unsigned short* A = Ag + (size_t)bz * sA;
  const unsigned short* B = Bg + (size_t)bz * sB;

  __shared__ __align__(16) unsigned short As[128 * 64];
  __shared__ __align__(16) unsigned short Bs[128 * 64];

  const int tid = threadIdx.x;
  const int lane = tid & 63;
  const int wave = tid >> 6;
  const int wm = (wave >> 1) * 64;
  const int wn = (wave & 1) * 64;
  const int lr = lane & 15;
  const int lg = lane >> 4;

  const int srow = lane >> 3;
  const int scol = ((lane & 7) ^ srow) * 8;

  f32x4 acc[4][4];
#pragma unroll
  for (int i = 0; i < 4; i++)
#pragma unroll
    for (int j = 0; j < 4; j++) acc[i][j] = (f32x4){0.f, 0.f, 0.f, 0.f};

  const unsigned short* Abase = A + (size_t)(mb + wave * 32 + srow) * lda + scol;
  const unsigned short* Bbase = B + (size_t)(nb + wave * 32 + srow) * ldb + scol;

  for (int kb = 0; kb < K; kb += 64) {
#pragma unroll
    for (int c = 0; c < 4; c++)
      glds16(Abase + (size_t)(c * 8) * lda + kb, &As[(wave * 32 + c * 8) * 64]);
#pragma unroll
    for (int c = 0; c < 4; c++)
      glds16(Bbase + (size_t)(c * 8) * ldb + kb, &Bs[(wave * 32 + c * 8) * 64]);
    __syncthreads();

    short8 af[2][4], bfb[2][4];
#pragma unroll
    for (int h = 0; h < 2; h++) {
      const int swz = ((h * 4 + lg) ^ (lr & 7)) * 8;
#pragma unroll
      for (int i = 0; i < 4; i++) {
        af[h][i] = *(const short8*)&As[(wm + 16 * i + lr) * 64 + swz];
        bfb[h][i] = *(const short8*)&Bs[(wn + 16 * i + lr) * 64 + swz];
      }
    }
#pragma unroll
    for (int h = 0; h < 2; h++)
#pragma unroll
      for (int i = 0; i < 4; i++)
#pragma unroll
        for (int j = 0; j < 4; j++)
          acc[i][j] = __builtin_amdgcn_mfma_f32_16x16x32_bf16(af[h][i], bfb[h][j], acc[i][j], 0, 0, 0);
    __syncthreads();
  }

  const size_t cb = (size_t)bz * sC;
#pragma unroll
  for (int i = 0; i < 4; i++) {
#pragma unroll
    for (int j = 0; j < 4; j++) {
      int oc = nb + wn + 16 * j + lr;
#pragma unroll
      for (int r = 0; r < 4; r++) {
        int orow = mb + wm + 16 * i + lg * 4 + r;
        float v = acc[i][j][r] * alpha;
        size_t idx = cb + (size_t)orow * ldc + oc;
        if (EPI == E_F32) {
          ((float*)Cg)[idx] = v;
        } else if (EPI == E_BF16) {
          ((unsigned short*)Cg)[idx] = f2bf(v);
        } else if (EPI == E_GATE) {
          float g = G[idx];
          float sw = g / (1.0f + expf(-g));
          ((unsigned short*)Cg)[idx] = f2bf(sw * v);
        } else {
          ((float*)Cg)[idx] = X1[idx] + X2[idx] + v;
        }
      }
    }
  }
}

// ---------------- fused flash attention --------------------------------------
// grid (16 qblocks, 16 heads), 256 thr. Per wave: 32 Q-rows.
// K/V^T 64-tiles double-buffered in LDS (glds16 + XOR swizzle).
__global__ __launch_bounds__(256) void flash_attn(
    const unsigned short* __restrict__ Qg, const unsigned short* __restrict__ Kg,
    const unsigned short* __restrict__ Vt, unsigned short* __restrict__ Og,
    int ldq, int ldo)
{
  const int qb = blockIdx.x;
  const int h = blockIdx.y;
  const int tid = threadIdx.x;
  const int lane = tid & 63;
  const int w = tid >> 6;
  const int lr = lane & 15;
  const int lg = lane >> 4;

  __shared__ __align__(16) unsigned short KsL[2][64 * 64];
  __shared__ __align__(16) unsigned short VsL[2][64 * 64];
  __shared__ __align__(16) unsigned short Ps[4][32 * 64];

  const int srow = lane >> 3;        // 0..7
  const int scol = ((lane & 7) ^ srow) * 8;

  // Q fragments (A-operand): row=lr, k=lg*8+j
  short8 qf[2][2];
#pragma unroll
  for (int i = 0; i < 2; i++)
#pragma unroll
    for (int kk = 0; kk < 2; kk++)
      qf[i][kk] = *(const short8*)(Qg +
          (size_t)(qb * 128 + w * 32 + i * 16 + lr) * ldq + h * 64 + kk * 32 + lg * 8);

  f32x4 acc_o[2][4];
  float m_st[2][4], l_st[2][4];
#pragma unroll
  for (int i = 0; i < 2; i++)
#pragma unroll
    for (int j = 0; j < 4; j++) acc_o[i][j] = (f32x4){0.f, 0.f, 0.f, 0.f};
#pragma unroll
  for (int i = 0; i < 2; i++)
#pragma unroll
    for (int r = 0; r < 4; r++) { m_st[i][r] = -1e30f; l_st[i][r] = 0.f; }

  const int ntiles = 2 * qb + 2;
  const int qmin = qb * 128 + w * 32;

  auto stage = [&](int t, int buf) {
#pragma unroll
    for (int c = 0; c < 2; c++) {
      glds16(Kg + (size_t)(t * 64 + w * 16 + c * 8 + srow) * ldq + h * 64 + scol,
             &KsL[buf][(w * 16 + c * 8) * 64]);
      glds16(Vt + (size_t)(h * 64 + w * 16 + c * 8 + srow) * L_SEQ + t * 64 + scol,
             &VsL[buf][(w * 16 + c * 8) * 64]);
    }
  };

  stage(0, 0);
  __syncthreads();
  int buf = 0;

  for (int t = 0; t < ntiles; t++) {
    if (t + 1 < ntiles) stage(t + 1, buf ^ 1);

    // ---- S = Q K^T (32x64) ----
    f32x4 sa[2][4];
#pragma unroll
    for (int i = 0; i < 2; i++)
#pragma unroll
      for (int j = 0; j < 4; j++) sa[i][j] = (f32x4){0.f, 0.f, 0.f, 0.f};
#pragma unroll
    for (int kk = 0; kk < 2; kk++) {
      short8 kf[4];
#pragma unroll
      for (int j = 0; j < 4; j++)
        kf[j] = *(const short8*)&KsL[buf][(j * 16 + lr) * 64 + ((kk * 4 + lg) ^ (lr & 7)) * 8];
#pragma unroll
      for (int i = 0; i < 2; i++)
#pragma unroll
        for (int j = 0; j < 4; j++)
          sa[i][j] = __builtin_amdgcn_mfma_f32_16x16x32_bf16(qf[i][kk], kf[j], sa[i][j], 0, 0, 0);
    }

    // ---- scale + causal mask ----
    const bool diag = (t * 64 + 63) > qmin;
#pragma unroll
    for (int i = 0; i < 2; i++)
#pragma unroll
      for (int j = 0; j < 4; j++)
#pragma unroll
        for (int r = 0; r < 4; r++) {
          float s = sa[i][j][r] * 0.125f;
          if (diag) {
            int kg = t * 64 + j * 16 + lr;
            int qg = qmin + i * 16 + lg * 4 + r;
            if (kg > qg) s = -1e30f;
          }
          sa[i][j][r] = s;
        }

    // ---- online softmax ----
    float fsc[2][4], mnew[2][4];
#pragma unroll
    for (int i = 0; i < 2; i++)
#pragma unroll
      for (int r = 0; r < 4; r++) {
        float mx = fmaxf(fmaxf(sa[i][0][r], sa[i][1][r]), fmaxf(sa[i][2][r], sa[i][3][r]));
        mx = rmax16(mx);
        float mn = fmaxf(m_st[i][r], mx);
        mnew[i][r] = mn;
        fsc[i][r] = __expf(m_st[i][r] - mn);
        m_st[i][r] = mn;
      }
#pragma unroll
    for (int i = 0; i < 2; i++)
#pragma unroll
      for (int r = 0; r < 4; r++) {
        float ls = 0.f;
#pragma unroll
        for (int j = 0; j < 4; j++) {
          float p = __expf(sa[i][j][r] - mnew[i][r]);
          sa[i][j][r] = p;
          ls += p;
        }
        ls = rsum16(ls);
        l_st[i][r] = l_st[i][r] * fsc[i][r] + ls;
      }
#pragma unroll
    for (int i = 0; i < 2; i++)
#pragma unroll
      for (int j = 0; j < 4; j++)
#pragma unroll
        for (int r = 0; r < 4; r++) acc_o[i][j][r] *= fsc[i][r];

    // ---- P -> LDS (bf16, swizzled) ----
#pragma unroll
    for (int i = 0; i < 2; i++)
#pragma unroll
      for (int j = 0; j < 4; j++)
#pragma unroll
        for (int r = 0; r < 4; r++) {
          int qrl = lg * 4 + r;
          int idx = (i * 16 + qrl) * 64 + (((j * 2 + (lr >> 3)) ^ (qrl & 7)) * 8) + (lr & 7);
          Ps[w][idx] = f2bf(sa[i][j][r]);
        }

    // ---- O += P V ----
#pragma unroll
    for (int kk = 0; kk < 2; kk++) {
      short8 pf[2], vf[4];
#pragma unroll
      for (int i = 0; i < 2; i++)
        pf[i] = *(const short8*)&Ps[w][(i * 16 + lr) * 64 + ((kk * 4 + lg) ^ (lr & 7)) * 8];
#pragma unroll
      for (int j = 0; j < 4; j++)
        vf[j] = *(const short8*)&VsL[buf][(j * 16 + lr) * 64 + ((kk * 4 + lg) ^ (lr & 7)) * 8];
#pragma unroll
      for (int i = 0; i < 2; i++)
#pragma unroll
        for (int j = 0; j < 4; j++)
          acc_o[i][j] = __builtin_amdgcn_mfma_f32_16x16x32_bf16(pf[i], vf[j], acc_o[i][j], 0, 0, 0);
    }

    __syncthreads();
    buf ^= 1;
  }

  // ---- epilogue: O /= l ----
  float inv[2][4];
#pragma unroll
  for (int i = 0; i < 2; i++)
#pragma unroll
    for (int r = 0; r < 4; r++) inv[i][r] = 1.0f / l_st[i][r];
#pragma unroll
  for (int i = 0; i < 2; i++)
#pragma unroll
    for (int j = 0; j < 4; j++)
#pragma unroll
      for (int r = 0; r < 4; r++) {
        size_t row = qmin + i * 16 + lg * 4 + r;
        Og[row * ldo + h * 64 + j * 16 + lr] = f2bf(acc_o[i][j][r] * inv[i][r]);
      }
}

__global__ __launch_bounds__(256) void rmsnorm_kernel(
    const float* __restrict__ x, const float* __restrict__ scale,
    unsigned short* __restrict__ out)
{
  int row = blockIdx.x;
  const float* xr = x + (size_t)row * DMODEL;
  int tid = threadIdx.x;
  float v[4];
  float ss = 0.f;
#pragma unroll
  for (int i = 0; i < 4; i++) {
    v[i] = xr[tid + 256 * i];
    ss += v[i] * v[i];
  }
#pragma unroll
  for (int o = 32; o > 0; o >>= 1) ss += __shfl_xor(ss, o);
  __shared__ float red[4];
  if ((tid & 63) == 0) red[tid >> 6] = ss;
  __syncthreads();
  ss = red[0] + red[1] + red[2] + red[3];
  float inv = rsqrtf(ss / DMODEL + 1e-6f);
#pragma unroll
  for (int i = 0; i < 4; i++) {
    int d = tid + 256 * i;
    out[(size_t)row * DMODEL + d] = f2bf(v[i] * inv * scale[d]);
  }
}

template <typename Tin>
__global__ __launch_bounds__(256) void transpose_to_bf16(
    const Tin* __restrict__ in, unsigned short* __restrict__ out,
    int ld_in, int ld_out)
{
  __shared__ float tile[32][33];
  int c0 = blockIdx.x * 32;
  int r0 = blockIdx.y * 32;
  int tx = threadIdx.x;
  int ty = threadIdx.y;
#pragma unroll
  for (int j = 0; j < 32; j += 8)
    tile[ty + j][tx] = toF(in[(size_t)(r0 + ty + j) * ld_in + c0 + tx]);
  __syncthreads();
#pragma unroll
  for (int j = 0; j < 32; j += 8)
    out[(size_t)(c0 + ty + j) * ld_out + r0 + tx] = f2bf(tile[tx][ty + j]);
}

__global__ __launch_bounds__(256) void convert_f2b_kernel(
    const float* __restrict__ in, unsigned short* __restrict__ out, size_t n)
{
  size_t i = ((size_t)blockIdx.x * 256 + threadIdx.x) * 4;
  if (i + 3 < n) {
    float4 v = *(const float4*)(in + i);
    out[i] = f2bf(v.x);
    out[i + 1] = f2bf(v.y);
    out[i + 2] = f2bf(v.z);
    out[i + 3] = f2bf(v.w);
  }
}

__global__ __launch_bounds__(256) void embed_kernel(
    const int* __restrict__ ids, const float* __restrict__ emb,
    const float* __restrict__ pos, float* __restrict__ x)
{
  int l = blockIdx.x;
  int id = ids[l];
#pragma unroll
  for (int i = 0; i < 4; i++) {
    int d = threadIdx.x + 256 * i;
    x[(size_t)l * DMODEL + d] = emb[(size_t)id * DMODEL + d] + pos[(size_t)l * DMODEL + d];
  }
}

extern "C" void kernel_launch(void* const* d_in, const int* in_sizes, int n_in,
                              void* d_out, int out_size, void* d_ws, size_t ws_size,
                              hipStream_t stream)
{
  const int L = L_SEQ, D = DMODEL, F = FFN_F, V = VOCAB;
  const int* ids = (const int*)d_in[0];
  const float* embed = (const float*)d_in[1];
  const float* pos = (const float*)d_in[2];
  const float* wq = (const float*)d_in[3];
  const float* wk = (const float*)d_in[4];
  const float* wv = (const float*)d_in[5];
  const float* wo = (const float*)d_in[6];
  const float* gatew = (const float*)d_in[7];
  const float* valw = (const float*)d_in[8];
  const float* ffow = (const float*)d_in[9];
  const float* ln1 = (const float*)d_in[10];
  const float* ln2 = (const float*)d_in[11];
  const float* lnf = (const float*)d_in[12];

  char* ws = (char*)d_ws;
  size_t off = 0;
  auto alloc = [&](size_t bytes) -> void* {
    void* p = ws + off;
    off += (bytes + 255) & ~(size_t)255;
    return p;
  };
  float* x = (float*)alloc((size_t)L * D * 4);
  unsigned short* xn = (unsigned short*)alloc((size_t)L * D * 2);
  unsigned short* qkvb = (unsigned short*)alloc((size_t)L * 3 * D * 2);
  unsigned short* vtb = (unsigned short*)alloc((size_t)L * D * 2);
  unsigned short* atb = (unsigned short*)alloc((size_t)L * D * 2);
  float* afp = (float*)alloc((size_t)L * D * 4);
  unsigned short* hb = (unsigned short*)alloc((size_t)L * F * 2);
  unsigned short* wqt = (unsigned short*)alloc((size_t)D * D * 2);  // wqt/wkt/wvt contiguous
  unsigned short* wkt = (unsigned short*)alloc((size_t)D * D * 2);
  unsigned short* wvt = (unsigned short*)alloc((size_t)D * D * 2);
  unsigned short* wot = (unsigned short*)alloc((size_t)D * D * 2);
  unsigned short* gt = (unsigned short*)alloc((size_t)D * F * 2);
  unsigned short* vtw = (unsigned short*)alloc((size_t)D * F * 2);
  unsigned short* fot = (unsigned short*)alloc((size_t)F * D * 2);
  unsigned short* embb = (unsigned short*)alloc((size_t)V * D * 2);

  float* gbuf = (float*)d_out;  // scratch; logits overwrite later

  dim3 blk(256);
  dim3 blkT(32, 8);

  auto gemmF = [&](int epi, const unsigned short* A, const unsigned short* B, void* C,
                   int M, int N, int K, int lda, int ldb, int ldc,
                   long long sA, long long sB, long long sC, int batch, float alpha,
                   int causal, const float* G, const float* X1, const float* X2) {
    dim3 grid(N / 128, M / 128, batch);
    if (epi == E_F32)
      gemm_fast<E_F32><<<grid, blk, 0, stream>>>(A, B, C, M, N, K, lda, ldb, ldc, sA, sB, sC, alpha, causal, G, X1, X2);
    else if (epi == E_BF16)
      gemm_fast<E_BF16><<<grid, blk, 0, stream>>>(A, B, C, M, N, K, lda, ldb, ldc, sA, sB, sC, alpha, causal, G, X1, X2);
    else if (epi == E_GATE)
      gemm_fast<E_GATE><<<grid, blk, 0, stream>>>(A, B, C, M, N, K, lda, ldb, ldc, sA, sB, sC, alpha, causal, G, X1, X2);
    else
      gemm_fast<E_ADD><<<grid, blk, 0, stream>>>(A, B, C, M, N, K, lda, ldb, ldc, sA, sB, sC, alpha, causal, G, X1, X2);
  };

  embed_kernel<<<L, blk, 0, stream>>>(ids, embed, pos, x);
  convert_f2b_kernel<<<(unsigned)((size_t)V * D / 1024), blk, 0, stream>>>(embed, embb, (size_t)V * D);

  for (int i = 0; i < NLAYER; i++) {
    const float* wqi = wq + (size_t)i * D * D;
    const float* wki = wk + (size_t)i * D * D;
    const float* wvi = wv + (size_t)i * D * D;
    const float* woi = wo + (size_t)i * D * D;
    const float* gi = gatew + (size_t)i * D * F;
    const float* vi = valw + (size_t)i * D * F;
    const float* fi = ffow + (size_t)i * F * D;

    transpose_to_bf16<float><<<dim3(D / 32, D / 32), blkT, 0, stream>>>(wqi, wqt, D, D);
    transpose_to_bf16<float><<<dim3(D / 32, D / 32), blkT, 0, stream>>>(wki, wkt, D, D);
    transpose_to_bf16<float><<<dim3(D / 32, D / 32), blkT, 0, stream>>>(wvi, wvt, D, D);
    transpose_to_bf16<float><<<dim3(D / 32, D / 32), blkT, 0, stream>>>(woi, wot, D, D);
    transpose_to_bf16<float><<<dim3(F / 32, D / 32), blkT, 0, stream>>>(gi, gt, F, D);
    transpose_to_bf16<float><<<dim3(F / 32, D / 32), blkT, 0, stream>>>(vi, vtw, F, D);
    transpose_to_bf16<float><<<dim3(D / 32, F / 32), blkT, 0, stream>>>(fi, fot, D, F);

    rmsnorm_kernel<<<L, blk, 0, stream>>>(x, ln1 + (size_t)i * D, xn);

    // fused QKV projection: wqt/wkt/wvt are one contiguous [3072][1024] matrix
    gemmF(E_BF16, xn, wqt, qkvb, L, 3 * D, D, D, D, 3 * D, 0, 0, 0, 1, 1.0f, 0, nullptr, nullptr, nullptr);

    // V^T for flash PV: [D][L] from qkvb's V section
    transpose_to_bf16<unsigned short><<<dim3(D / 32, L / 32), blkT, 0, stream>>>(
        qkvb + 2 * D, vtb, 3 * D, L);

    flash_attn<<<dim3(16, 16), blk, 0, stream>>>(qkvb, qkvb + D, vtb, atb, 3 * D, D);

    gemmF(E_F32, atb, wot, afp, L, D, D, D, D, D, 0, 0, 0, 1, 1.0f, 0, nullptr, nullptr, nullptr);

    rmsnorm_kernel<<<L, blk, 0, stream>>>(x, ln2 + (size_t)i * D, xn);

    gemmF(E_F32, xn, gt, gbuf, L, F, D, D, D, F, 0, 0, 0, 1, 1.0f, 0, nullptr, nullptr, nullptr);
    gemmF(E_GATE, xn, vtw, hb, L, F, D, D, D, F, 0, 0, 0, 1, 1.0f, 0, gbuf, nullptr, nullptr);
    gemmF(E_ADD, hb, fot, x, L, D, F, F, F, D, 0, 0, 0, 1, 1.0f, 0, nullptr, x, afp);
  }

  rmsnorm_kernel<<<L, blk, 0, stream>>>(x, lnf, xn);
  gemmF(E_F32, xn, embb, d_out, L, V, D, D, D, V, 0, 0, 0, 1, 1.0f, 0, nullptr, nullptr, nullptr);
}

// Round 4
// 1445.166 us; speedup vs baseline: 2.1100x; 1.0376x over previous
//
#include <hip/hip_runtime.h>
#include <cstdint>
#include <cstddef>

#define L_SEQ 2048
#define DMODEL 1024
#define NHEAD 16
#define DHEAD 64
#define FFN_F 4096
#define VOCAB 32000
#define NLAYER 4

typedef __attribute__((ext_vector_type(8))) short short8;
typedef __attribute__((ext_vector_type(4))) float f32x4;

__device__ __forceinline__ unsigned short f2bf(float f) {
  unsigned int u = __float_as_uint(f);
  u += 0x7fffu + ((u >> 16) & 1u);
  return (unsigned short)(u >> 16);
}
__device__ __forceinline__ float b2f(unsigned short h) {
  return __uint_as_float(((unsigned int)h) << 16);
}
__device__ __forceinline__ float toF(float v) { return v; }
__device__ __forceinline__ float toF(unsigned short v) { return b2f(v); }

__device__ __forceinline__ void glds16(const unsigned short* g, unsigned short* l) {
  __builtin_amdgcn_global_load_lds(
      (const __attribute__((address_space(1))) unsigned int*)g,
      (__attribute__((address_space(3))) unsigned int*)l, 16, 0, 0);
}

__device__ __forceinline__ float rmax16(float v) {
  v = fmaxf(v, __shfl_xor(v, 1));
  v = fmaxf(v, __shfl_xor(v, 2));
  v = fmaxf(v, __shfl_xor(v, 4));
  v = fmaxf(v, __shfl_xor(v, 8));
  return v;
}
__device__ __forceinline__ float rsum16(float v) {
  v += __shfl_xor(v, 1);
  v += __shfl_xor(v, 2);
  v += __shfl_xor(v, 4);
  v += __shfl_xor(v, 8);
  return v;
}

enum { E_F32 = 0, E_BF16 = 1, E_SWIGLU = 2, E_ADD = 3 };

// ---------------- dense GEMM: C[M,N] = alpha*A[M,K]*B[N,K]^T -----------------
// 2-phase double-buffered prefetch (T3-minimum) + bijective XCD swizzle.
// All dims: M,N %128, K %64.
template <int EPI>
__global__ __launch_bounds__(256) void gemm_fast(
    const unsigned short* __restrict__ A, const unsigned short* __restrict__ B,
    void* __restrict__ Cg, int M, int N, int K, int lda, int ldb, int ldc,
    float alpha, int nbx,
    const float* __restrict__ X1, const float* __restrict__ X2)
{
  // linearized grid; bijective XCD remap (m204): XCD k owns a contiguous chunk
  const int nwg = gridDim.x;
  const int orig = blockIdx.x;
  const int q = nwg >> 3, r = nwg & 7;
  const int xcd = orig & 7, rest = orig >> 3;
  const int wgid = (xcd < r ? xcd * (q + 1) : r * (q + 1) + (xcd - r) * q) + rest;
  const int bx = wgid % nbx, by = wgid / nbx;
  const int mb = by * 128;
  const int nb = bx * 128;

  __shared__ __align__(16) unsigned short As[2][128 * 64];
  __shared__ __align__(16) unsigned short Bs[2][128 * 64];

  const int tid = threadIdx.x;
  const int lane = tid & 63;
  const int wave = tid >> 6;
  const int wm = (wave >> 1) * 64;
  const int wn = (wave & 1) * 64;
  const int lr = lane & 15;
  const int lg = lane >> 4;

  const int srow = lane >> 3;                 // 0..7 within 8-row stripe
  const int scol = ((lane & 7) ^ srow) * 8;   // inverse-swizzled source col

  f32x4 acc[4][4];
#pragma unroll
  for (int i = 0; i < 4; i++)
#pragma unroll
    for (int j = 0; j < 4; j++) acc[i][j] = (f32x4){0.f, 0.f, 0.f, 0.f};

  const unsigned short* Abase = A + (size_t)(mb + wave * 32 + srow) * lda + scol;
  const unsigned short* Bbase = B + (size_t)(nb + wave * 32 + srow) * ldb + scol;

  auto stage = [&](int kb, int b) {
#pragma unroll
    for (int c = 0; c < 4; c++)
      glds16(Abase + (size_t)(c * 8) * lda + kb, &As[b][(wave * 32 + c * 8) * 64]);
#pragma unroll
    for (int c = 0; c < 4; c++)
      glds16(Bbase + (size_t)(c * 8) * ldb + kb, &Bs[b][(wave * 32 + c * 8) * 64]);
  };

  stage(0, 0);
  __syncthreads();  // vmcnt(0) drain + barrier
  int cur = 0;
  const int nk = K >> 6;

  for (int t = 0; t < nk; ++t) {
    if (t + 1 < nk) stage((t + 1) << 6, cur ^ 1);  // prefetch in flight over MFMA

    short8 af[2][4], bfb[2][4];
#pragma unroll
    for (int h = 0; h < 2; h++) {
      const int swz = ((h * 4 + lg) ^ (lr & 7)) * 8;
#pragma unroll
      for (int i = 0; i < 4; i++) {
        af[h][i] = *(const short8*)&As[cur][(wm + 16 * i + lr) * 64 + swz];
        bfb[h][i] = *(const short8*)&Bs[cur][(wn + 16 * i + lr) * 64 + swz];
      }
    }
#pragma unroll
    for (int h = 0; h < 2; h++)
#pragma unroll
      for (int i = 0; i < 4; i++)
#pragma unroll
        for (int j = 0; j < 4; j++)
          acc[i][j] = __builtin_amdgcn_mfma_f32_16x16x32_bf16(af[h][i], bfb[h][j], acc[i][j], 0, 0, 0);

    __syncthreads();  // drains prefetch vmcnt + syncs LDS reuse
    cur ^= 1;
  }

#pragma unroll
  for (int i = 0; i < 4; i++) {
#pragma unroll
    for (int j = 0; j < 4; j++) {
      int oc = nb + wn + 16 * j + lr;
#pragma unroll
      for (int r4 = 0; r4 < 4; r4++) {
        int orow = mb + wm + 16 * i + lg * 4 + r4;
        float v = acc[i][j][r4] * alpha;
        size_t idx = (size_t)orow * ldc + oc;
        if (EPI == E_F32) {
          ((float*)Cg)[idx] = v;
        } else if (EPI == E_BF16) {
          ((unsigned short*)Cg)[idx] = f2bf(v);
        } else if (EPI == E_SWIGLU) {
          // B rows interleaved: even col = gate, odd col = val (same ffn col)
          float other = __shfl_xor(v, 1);
          float g = (lane & 1) ? other : v;
          float vv = (lane & 1) ? v : other;
          float sw = g / (1.0f + expf(-g)) * vv;
          if (!(lane & 1))
            ((unsigned short*)Cg)[(size_t)orow * ldc + (oc >> 1)] = f2bf(sw);
        } else {  // E_ADD
          ((float*)Cg)[idx] = X1[idx] + X2[idx] + v;
        }
      }
    }
  }
}

// ---------------- fused flash attention --------------------------------------
__global__ __launch_bounds__(256) void flash_attn(
    const unsigned short* __restrict__ Qg, const unsigned short* __restrict__ Kg,
    const unsigned short* __restrict__ Vt, unsigned short* __restrict__ Og,
    int ldq, int ldo)
{
  const int qb = blockIdx.x;
  const int h = blockIdx.y;
  const int tid = threadIdx.x;
  const int lane = tid & 63;
  const int w = tid >> 6;
  const int lr = lane & 15;
  const int lg = lane >> 4;

  __shared__ __align__(16) unsigned short KsL[2][64 * 64];
  __shared__ __align__(16) unsigned short VsL[2][64 * 64];
  __shared__ __align__(16) unsigned short Ps[4][32 * 64];

  const int srow = lane >> 3;
  const int scol = ((lane & 7) ^ srow) * 8;

  short8 qf[2][2];
#pragma unroll
  for (int i = 0; i < 2; i++)
#pragma unroll
    for (int kk = 0; kk < 2; kk++)
      qf[i][kk] = *(const short8*)(Qg +
          (size_t)(qb * 128 + w * 32 + i * 16 + lr) * ldq + h * 64 + kk * 32 + lg * 8);

  f32x4 acc_o[2][4];
  float m_st[2][4], l_st[2][4];
#pragma unroll
  for (int i = 0; i < 2; i++)
#pragma unroll
    for (int j = 0; j < 4; j++) acc_o[i][j] = (f32x4){0.f, 0.f, 0.f, 0.f};
#pragma unroll
  for (int i = 0; i < 2; i++)
#pragma unroll
    for (int r = 0; r < 4; r++) { m_st[i][r] = -1e30f; l_st[i][r] = 0.f; }

  const int ntiles = 2 * qb + 2;
  const int qmin = qb * 128 + w * 32;

  auto stage = [&](int t, int buf) {
#pragma unroll
    for (int c = 0; c < 2; c++) {
      glds16(Kg + (size_t)(t * 64 + w * 16 + c * 8 + srow) * ldq + h * 64 + scol,
             &KsL[buf][(w * 16 + c * 8) * 64]);
      glds16(Vt + (size_t)(h * 64 + w * 16 + c * 8 + srow) * L_SEQ + t * 64 + scol,
             &VsL[buf][(w * 16 + c * 8) * 64]);
    }
  };

  stage(0, 0);
  __syncthreads();
  int buf = 0;

  for (int t = 0; t < ntiles; t++) {
    if (t + 1 < ntiles) stage(t + 1, buf ^ 1);

    f32x4 sa[2][4];
#pragma unroll
    for (int i = 0; i < 2; i++)
#pragma unroll
      for (int j = 0; j < 4; j++) sa[i][j] = (f32x4){0.f, 0.f, 0.f, 0.f};
#pragma unroll
    for (int kk = 0; kk < 2; kk++) {
      short8 kf[4];
#pragma unroll
      for (int j = 0; j < 4; j++)
        kf[j] = *(const short8*)&KsL[buf][(j * 16 + lr) * 64 + ((kk * 4 + lg) ^ (lr & 7)) * 8];
#pragma unroll
      for (int i = 0; i < 2; i++)
#pragma unroll
        for (int j = 0; j < 4; j++)
          sa[i][j] = __builtin_amdgcn_mfma_f32_16x16x32_bf16(qf[i][kk], kf[j], sa[i][j], 0, 0, 0);
    }

    const bool diag = (t * 64 + 63) > qmin;
#pragma unroll
    for (int i = 0; i < 2; i++)
#pragma unroll
      for (int j = 0; j < 4; j++)
#pragma unroll
        for (int r = 0; r < 4; r++) {
          float s = sa[i][j][r] * 0.125f;
          if (diag) {
            int kg = t * 64 + j * 16 + lr;
            int qg = qmin + i * 16 + lg * 4 + r;
            if (kg > qg) s = -1e30f;
          }
          sa[i][j][r] = s;
        }

    float fsc[2][4], mnew[2][4];
#pragma unroll
    for (int i = 0; i < 2; i++)
#pragma unroll
      for (int r = 0; r < 4; r++) {
        float mx = fmaxf(fmaxf(sa[i][0][r], sa[i][1][r]), fmaxf(sa[i][2][r], sa[i][3][r]));
        mx = rmax16(mx);
        float mn = fmaxf(m_st[i][r], mx);
        mnew[i][r] = mn;
        fsc[i][r] = __expf(m_st[i][r] - mn);
        m_st[i][r] = mn;
      }
#pragma unroll
    for (int i = 0; i < 2; i++)
#pragma unroll
      for (int r = 0; r < 4; r++) {
        float ls = 0.f;
#pragma unroll
        for (int j = 0; j < 4; j++) {
          float p = __expf(sa[i][j][r] - mnew[i][r]);
          sa[i][j][r] = p;
          ls += p;
        }
        ls = rsum16(ls);
        l_st[i][r] = l_st[i][r] * fsc[i][r] + ls;
      }
#pragma unroll
    for (int i = 0; i < 2; i++)
#pragma unroll
      for (int j = 0; j < 4; j++)
#pragma unroll
        for (int r = 0; r < 4; r++) acc_o[i][j][r] *= fsc[i][r];

#pragma unroll
    for (int i = 0; i < 2; i++)
#pragma unroll
      for (int j = 0; j < 4; j++)
#pragma unroll
        for (int r = 0; r < 4; r++) {
          int qrl = lg * 4 + r;
          int idx = (i * 16 + qrl) * 64 + (((j * 2 + (lr >> 3)) ^ (qrl & 7)) * 8) + (lr & 7);
          Ps[w][idx] = f2bf(sa[i][j][r]);
        }

#pragma unroll
    for (int kk = 0; kk < 2; kk++) {
      short8 pf[2], vf[4];
#pragma unroll
      for (int i = 0; i < 2; i++)
        pf[i] = *(const short8*)&Ps[w][(i * 16 + lr) * 64 + ((kk * 4 + lg) ^ (lr & 7)) * 8];
#pragma unroll
      for (int j = 0; j < 4; j++)
        vf[j] = *(const short8*)&VsL[buf][(j * 16 + lr) * 64 + ((kk * 4 + lg) ^ (lr & 7)) * 8];
#pragma unroll
      for (int i = 0; i < 2; i++)
#pragma unroll
        for (int j = 0; j < 4; j++)
          acc_o[i][j] = __builtin_amdgcn_mfma_f32_16x16x32_bf16(pf[i], vf[j], acc_o[i][j], 0, 0, 0);
    }

    __syncthreads();
    buf ^= 1;
  }

  float inv[2][4];
#pragma unroll
  for (int i = 0; i < 2; i++)
#pragma unroll
    for (int r = 0; r < 4; r++) inv[i][r] = 1.0f / l_st[i][r];
#pragma unroll
  for (int i = 0; i < 2; i++)
#pragma unroll
    for (int j = 0; j < 4; j++)
#pragma unroll
      for (int r = 0; r < 4; r++) {
        size_t row = qmin + i * 16 + lg * 4 + r;
        Og[row * ldo + h * 64 + j * 16 + lr] = f2bf(acc_o[i][j][r] * inv[i][r]);
      }
}

__global__ __launch_bounds__(256) void rmsnorm_kernel(
    const float* __restrict__ x, const float* __restrict__ scale,
    unsigned short* __restrict__ out)
{
  int row = blockIdx.x;
  const float* xr = x + (size_t)row * DMODEL;
  int tid = threadIdx.x;
  float v[4];
  float ss = 0.f;
#pragma unroll
  for (int i = 0; i < 4; i++) {
    v[i] = xr[tid + 256 * i];
    ss += v[i] * v[i];
  }
#pragma unroll
  for (int o = 32; o > 0; o >>= 1) ss += __shfl_xor(ss, o);
  __shared__ float red[4];
  if ((tid & 63) == 0) red[tid >> 6] = ss;
  __syncthreads();
  ss = red[0] + red[1] + red[2] + red[3];
  float inv = rsqrtf(ss / DMODEL + 1e-6f);
#pragma unroll
  for (int i = 0; i < 4; i++) {
    int d = tid + 256 * i;
    out[(size_t)row * DMODEL + d] = f2bf(v[i] * inv * scale[d]);
  }
}

template <typename Tin>
__global__ __launch_bounds__(256) void transpose_to_bf16(
    const Tin* __restrict__ in, unsigned short* __restrict__ out,
    int ld_in, int ld_out)
{
  __shared__ float tile[32][33];
  int c0 = blockIdx.x * 32;
  int r0 = blockIdx.y * 32;
  int tx = threadIdx.x;
  int ty = threadIdx.y;
#pragma unroll
  for (int j = 0; j < 32; j += 8)
    tile[ty + j][tx] = toF(in[(size_t)(r0 + ty + j) * ld_in + c0 + tx]);
  __syncthreads();
#pragma unroll
  for (int j = 0; j < 32; j += 8)
    out[(size_t)(c0 + ty + j) * ld_out + r0 + tx] = f2bf(tile[tx][ty + j]);
}

// gate/val [D][F] -> interleaved-transposed [2F][D]: row 2c=gate col c, 2c+1=val col c
__global__ __launch_bounds__(256) void transpose_interleave2(
    const float* __restrict__ g, const float* __restrict__ v,
    unsigned short* __restrict__ out)
{
  __shared__ float tg[32][33], tv[32][33];
  int c0 = blockIdx.x * 32;  // F dim
  int d0 = blockIdx.y * 32;  // D dim
  int tx = threadIdx.x;
  int ty = threadIdx.y;
#pragma unroll
  for (int j = 0; j < 32; j += 8) {
    tg[ty + j][tx] = g[(size_t)(d0 + ty + j) * FFN_F + c0 + tx];
    tv[ty + j][tx] = v[(size_t)(d0 + ty + j) * FFN_F + c0 + tx];
  }
  __syncthreads();
#pragma unroll
  for (int j = 0; j < 32; j += 8) {
    out[(size_t)(2 * (c0 + ty + j)) * DMODEL + d0 + tx] = f2bf(tg[tx][ty + j]);
    out[(size_t)(2 * (c0 + ty + j) + 1) * DMODEL + d0 + tx] = f2bf(tv[tx][ty + j]);
  }
}

__global__ __launch_bounds__(256) void convert_f2b_kernel(
    const float* __restrict__ in, unsigned short* __restrict__ out, size_t n)
{
  size_t i = ((size_t)blockIdx.x * 256 + threadIdx.x) * 4;
  if (i + 3 < n) {
    float4 v = *(const float4*)(in + i);
    out[i] = f2bf(v.x);
    out[i + 1] = f2bf(v.y);
    out[i + 2] = f2bf(v.z);
    out[i + 3] = f2bf(v.w);
  }
}

__global__ __launch_bounds__(256) void embed_kernel(
    const int* __restrict__ ids, const float* __restrict__ emb,
    const float* __restrict__ pos, float* __restrict__ x)
{
  int l = blockIdx.x;
  int id = ids[l];
#pragma unroll
  for (int i = 0; i < 4; i++) {
    int d = threadIdx.x + 256 * i;
    x[(size_t)l * DMODEL + d] = emb[(size_t)id * DMODEL + d] + pos[(size_t)l * DMODEL + d];
  }
}

extern "C" void kernel_launch(void* const* d_in, const int* in_sizes, int n_in,
                              void* d_out, int out_size, void* d_ws, size_t ws_size,
                              hipStream_t stream)
{
  const int L = L_SEQ, D = DMODEL, F = FFN_F, V = VOCAB;
  const int* ids = (const int*)d_in[0];
  const float* embed = (const float*)d_in[1];
  const float* pos = (const float*)d_in[2];
  const float* wq = (const float*)d_in[3];
  const float* wk = (const float*)d_in[4];
  const float* wv = (const float*)d_in[5];
  const float* wo = (const float*)d_in[6];
  const float* gatew = (const float*)d_in[7];
  const float* valw = (const float*)d_in[8];
  const float* ffow = (const float*)d_in[9];
  const float* ln1 = (const float*)d_in[10];
  const float* ln2 = (const float*)d_in[11];
  const float* lnf = (const float*)d_in[12];

  char* ws = (char*)d_ws;
  size_t off = 0;
  auto alloc = [&](size_t bytes) -> void* {
    void* p = ws + off;
    off += (bytes + 255) & ~(size_t)255;
    return p;
  };
  float* x = (float*)alloc((size_t)L * D * 4);
  unsigned short* xn = (unsigned short*)alloc((size_t)L * D * 2);
  unsigned short* qkvb = (unsigned short*)alloc((size_t)L * 3 * D * 2);
  unsigned short* vtb = (unsigned short*)alloc((size_t)L * D * 2);
  unsigned short* atb = (unsigned short*)alloc((size_t)L * D * 2);
  float* afp = (float*)alloc((size_t)L * D * 4);
  unsigned short* hb = (unsigned short*)alloc((size_t)L * F * 2);
  unsigned short* wqt = (unsigned short*)alloc((size_t)D * D * 2);  // wqt/wkt/wvt contiguous
  unsigned short* wkt = (unsigned short*)alloc((size_t)D * D * 2);
  unsigned short* wvt = (unsigned short*)alloc((size_t)D * D * 2);
  unsigned short* wot = (unsigned short*)alloc((size_t)D * D * 2);
  unsigned short* gvt = (unsigned short*)alloc((size_t)2 * F * D * 2);
  unsigned short* fot = (unsigned short*)alloc((size_t)F * D * 2);
  unsigned short* embb = (unsigned short*)alloc((size_t)V * D * 2);

  dim3 blk(256);
  dim3 blkT(32, 8);

  auto gemmF = [&](int epi, const unsigned short* A, const unsigned short* B, void* C,
                   int M, int N, int K, int lda, int ldb, int ldc, float alpha,
                   const float* X1, const float* X2) {
    int nbx = N / 128;
    dim3 grid(nbx * (M / 128));
    if (epi == E_F32)
      gemm_fast<E_F32><<<grid, blk, 0, stream>>>(A, B, C, M, N, K, lda, ldb, ldc, alpha, nbx, X1, X2);
    else if (epi == E_BF16)
      gemm_fast<E_BF16><<<grid, blk, 0, stream>>>(A, B, C, M, N, K, lda, ldb, ldc, alpha, nbx, X1, X2);
    else if (epi == E_SWIGLU)
      gemm_fast<E_SWIGLU><<<grid, blk, 0, stream>>>(A, B, C, M, N, K, lda, ldb, ldc, alpha, nbx, X1, X2);
    else
      gemm_fast<E_ADD><<<grid, blk, 0, stream>>>(A, B, C, M, N, K, lda, ldb, ldc, alpha, nbx, X1, X2);
  };

  embed_kernel<<<L, blk, 0, stream>>>(ids, embed, pos, x);
  convert_f2b_kernel<<<(unsigned)((size_t)V * D / 1024), blk, 0, stream>>>(embed, embb, (size_t)V * D);

  for (int i = 0; i < NLAYER; i++) {
    const float* wqi = wq + (size_t)i * D * D;
    const float* wki = wk + (size_t)i * D * D;
    const float* wvi = wv + (size_t)i * D * D;
    const float* woi = wo + (size_t)i * D * D;
    const float* gi = gatew + (size_t)i * D * F;
    const float* vi = valw + (size_t)i * D * F;
    const float* fi = ffow + (size_t)i * F * D;

    transpose_to_bf16<float><<<dim3(D / 32, D / 32), blkT, 0, stream>>>(wqi, wqt, D, D);
    transpose_to_bf16<float><<<dim3(D / 32, D / 32), blkT, 0, stream>>>(wki, wkt, D, D);
    transpose_to_bf16<float><<<dim3(D / 32, D / 32), blkT, 0, stream>>>(wvi, wvt, D, D);
    transpose_to_bf16<float><<<dim3(D / 32, D / 32), blkT, 0, stream>>>(woi, wot, D, D);
    transpose_interleave2<<<dim3(F / 32, D / 32), blkT, 0, stream>>>(gi, vi, gvt);
    transpose_to_bf16<float><<<dim3(D / 32, F / 32), blkT, 0, stream>>>(fi, fot, D, F);

    rmsnorm_kernel<<<L, blk, 0, stream>>>(x, ln1 + (size_t)i * D, xn);

    // fused QKV projection
    gemmF(E_BF16, xn, wqt, qkvb, L, 3 * D, D, D, D, 3 * D, 1.0f, nullptr, nullptr);

    transpose_to_bf16<unsigned short><<<dim3(D / 32, L / 32), blkT, 0, stream>>>(
        qkvb + 2 * D, vtb, 3 * D, L);

    flash_attn<<<dim3(16, 16), blk, 0, stream>>>(qkvb, qkvb + D, vtb, atb, 3 * D, D);

    gemmF(E_F32, atb, wot, afp, L, D, D, D, D, D, 1.0f, nullptr, nullptr);

    rmsnorm_kernel<<<L, blk, 0, stream>>>(x, ln2 + (size_t)i * D, xn);

    // fused gate+val (interleaved weights) with swiglu epilogue; ldc = F
    gemmF(E_SWIGLU, xn, gvt, hb, L, 2 * F, D, D, D, F, 1.0f, nullptr, nullptr);
    gemmF(E_ADD, hb, fot, x, L, D, F, F, F, D, 1.0f, x, afp);
  }

  rmsnorm_kernel<<<L, blk, 0, stream>>>(x, lnf, xn);
  gemmF(E_F32, xn, embb, d_out, L, V, D, D, D, V, 1.0f, nullptr, nullptr);
}